// Round 17
// baseline (66.097 us; speedup 1.0000x reference)
//
#include <hip/hip_runtime.h>
#include <cmath>

typedef unsigned short u16;
typedef __attribute__((ext_vector_type(8))) short s8v;    // 8 bf16 (4 VGPRs)
typedef __attribute__((ext_vector_type(4))) float f4v;    // 16x16 acc / float4
typedef __attribute__((ext_vector_type(16))) float f16v;  // 32x32 acc

__device__ __forceinline__ u16 f2bf(float f) {
    union { float f; unsigned u; } v; v.f = f;
    unsigned r = v.u + 0x7FFFu + ((v.u >> 16) & 1u);   // RNE
    return (u16)(r >> 16);
}
// fast tanh: 1 - 2/(1+exp2(2x*log2e)); |err| ~1e-6
__device__ __forceinline__ float tanh_fast(float x) {
    float e = __builtin_amdgcn_exp2f(x * 2.88539008177792681f);
    return 1.f - 2.f * __builtin_amdgcn_rcpf(1.f + e);
}
// 16x16 subtile swizzled slot (gemm1 input staging; verified R5)
__device__ __forceinline__ int wslot(int row, int c) {
    return ((((c >> 2) << 6) | ((c & 3) << 4) | (row & 15)) ^ c);
}
// fragment-layout flat u16 index for element (n,k), 32x32 frags:
// lane = (n&31) + ((k>>3)&1)*32; j = k&7; tile (n>>5, k>>4)
__device__ __forceinline__ size_t fragoff(int n, int k) {
    return (((size_t)(n >> 5) * 64 + (k >> 4)) * 64 + (n & 31) + (((k >> 3) & 1) << 5)) * 8 + (k & 7);
}
// async global->LDS, 16B/lane; LDS dest wave-uniform, global src per-lane
__device__ __forceinline__ void gload_lds16(const u16* g, u16* l) {
    __builtin_amdgcn_global_load_lds(
        (const __attribute__((address_space(1))) void*)g,
        (__attribute__((address_space(3))) void*)l,
        16, 0, 0);
}

// ---------------------------------------------------------------------------
// prep (grid 32x32, 256 thr):  (R16 verbatim: R9 + obuf zeroing)
// ---------------------------------------------------------------------------
__launch_bounds__(256)
__global__ void cnf_prep(const float* __restrict__ x, const float* __restrict__ W1,
                         const float* __restrict__ W2, const float* __restrict__ W3,
                         u16* __restrict__ W2Tf, u16* __restrict__ VTf,
                         u16* __restrict__ xb, u16* __restrict__ W1T,
                         u16* __restrict__ W3Tf, float* __restrict__ trJ,
                         float* __restrict__ obuf)
{
    __shared__ float w2s[32][33];
    __shared__ __align__(16) float w1s[64][36];   // [i][p], 16B-aligned rows
    const int a = blockIdx.x * 32;   // p / k (rows of W2)
    const int b = blockIdx.y * 32;   // q / n (cols of W2)
    const int t = threadIdx.x;

    obuf[(blockIdx.y * 32 + blockIdx.x) * 256 + t] = 0.f;

    #pragma unroll
    for (int it = 0; it < 4; ++it) {
        int idx = t + it * 256;
        w2s[idx >> 5][idx & 31] = W2[(a + (idx >> 5)) * 1024 + b + (idx & 31)];
    }
    #pragma unroll
    for (int it = 0; it < 8; ++it) {
        int idx = t + it * 256;
        w1s[idx >> 5][idx & 31] = W1[(idx >> 5) * 1024 + a + (idx & 31)];
    }
    __syncthreads();

    #pragma unroll
    for (int it = 0; it < 4; ++it) {
        int idx = t + it * 256;
        int rr = idx >> 5, cc = idx & 31;
        W2Tf[fragoff(b + rr, a + cc)] = f2bf(w2s[cc][rr]);
    }
    {
        const int q = t >> 3, pg = t & 7;
        const float* w3row = W3 + (b + q) * 64;
        f4v u = f4v{0.f, 0.f, 0.f, 0.f};
        #pragma unroll
        for (int i4 = 0; i4 < 16; ++i4) {
            f4v w3v = *(const f4v*)&w3row[i4 * 4];
            #pragma unroll
            for (int s = 0; s < 4; ++s) {
                f4v wv = *(const f4v*)&w1s[i4 * 4 + s][pg * 4];
                u += w3v[s] * wv;
            }
        }
        #pragma unroll
        for (int j = 0; j < 4; ++j) {
            const int pp = pg * 4 + j;
            VTf[fragoff(b + q, a + pp)] = f2bf(w2s[pp][q] * u[j]);
        }
    }
    {
        int bid = blockIdx.y * 32 + blockIdx.x;
        int e = bid * 256 + t;
        xb[e] = f2bf(x[(e >> 6) * 65 + 1 + (e & 63)]);
    }
    if (blockIdx.y == 0) {
        int pp = t >> 3, i0 = (t & 7) * 8;
        s8v v;
        #pragma unroll
        for (int j = 0; j < 8; ++j) v[j] = (short)f2bf(w1s[i0 + j][pp]);
        *(s8v*)&W1T[(a + pp) * 64 + i0] = v;
        if (t < 128) trJ[blockIdx.x * 128 + t] = 0.f;
    }
    if (blockIdx.y == 1) {
        int idx = blockIdx.x * 256 + t;
        int n = idx & 63, k0 = (idx >> 6) * 8;
        s8v v;
        #pragma unroll
        for (int j = 0; j < 8; ++j) v[j] = (short)f2bf(W3[(k0 + j) * 64 + n]);
        *(s8v*)&W3Tf[fragoff(n, k0)] = v;
    }
}

// ---------------------------------------------------------------------------
// gemm1 (MFMA 16x16x32): h1 = tanh(xb @ W1T^T + b1), g1 = 1-h1^2
// OUTPUT IN 32x32 A-FRAGMENT LAYOUT (h1f/g1f).  (R12 verbatim, verified)
// ---------------------------------------------------------------------------
__launch_bounds__(256)
__global__ void cnf_gemm1(const u16* __restrict__ xb, const u16* __restrict__ W1T,
                          const float* __restrict__ b1,
                          u16* __restrict__ h1f, u16* __restrict__ g1f)
{
    __shared__ __align__(16) u16 lds[12 * 1024];   // 24 KB input staging
    __shared__ __align__(16) u16 hls[128 * 64];    // 16 KB
    __shared__ __align__(16) u16 gls[128 * 64];    // 16 KB
    const int t = threadIdx.x;
    const int wave = t >> 6, lane = t & 63;
    const int wm = wave >> 1, wn = wave & 1;
    const int g = lane >> 4, lr = lane & 15;
    const int arow0 = blockIdx.x * 128, bcol0 = blockIdx.y * 64;

    #pragma unroll
    for (int i = 0; i < 4; ++i) {
        int ch = t + i * 256, row = ch >> 3, c = ch & 7;
        *(s8v*)&lds[(row >> 4) * 1024 + wslot(row, c) * 8] =
            *(const s8v*)&xb[(arow0 + row) * 64 + c * 8];
    }
    #pragma unroll
    for (int i = 0; i < 2; ++i) {
        int ch = t + i * 256, row = ch >> 3, c = ch & 7;
        *(s8v*)&lds[(8 + (row >> 4)) * 1024 + wslot(row, c) * 8] =
            *(const s8v*)&W1T[(bcol0 + row) * 64 + c * 8];
    }
    __syncthreads();

    f4v acc[4][2];
    #pragma unroll
    for (int mi = 0; mi < 4; ++mi)
        #pragma unroll
        for (int ni = 0; ni < 2; ++ni) acc[mi][ni] = f4v{0.f,0.f,0.f,0.f};

    #pragma unroll
    for (int ks = 0; ks < 2; ++ks) {
        const int lo = (ks * 64 + (lane ^ ((ks * 4 + g) & 7))) * 8;
        s8v af[4], bf[2];
        #pragma unroll
        for (int mi = 0; mi < 4; ++mi) af[mi] = *(const s8v*)&lds[(wm * 4 + mi) * 1024 + lo];
        #pragma unroll
        for (int ni = 0; ni < 2; ++ni) bf[ni] = *(const s8v*)&lds[(8 + wn * 2 + ni) * 1024 + lo];
        #pragma unroll
        for (int mi = 0; mi < 4; ++mi)
            #pragma unroll
            for (int ni = 0; ni < 2; ++ni)
                acc[mi][ni] = __builtin_amdgcn_mfma_f32_16x16x32_bf16(af[mi], bf[ni], acc[mi][ni], 0, 0, 0);
    }

    #pragma unroll
    for (int mi = 0; mi < 4; ++mi) {
        const int rowl = wm * 64 + mi * 16 + g * 4;
        #pragma unroll
        for (int ni = 0; ni < 2; ++ni) {
            const int coll = wn * 32 + ni * 16 + lr;
            const float bv = b1[bcol0 + coll];
            const int cc = coll >> 3, jj = coll & 7;
            #pragma unroll
            for (int r = 0; r < 4; ++r) {
                const int row = rowl + r;
                float h = tanh_fast(acc[mi][ni][r] + bv);
                int idx = row * 64 + ((cc ^ (row & 7)) << 3) + jj;
                hls[idx] = f2bf(h);
                gls[idx] = f2bf(1.f - h * h);
            }
        }
    }
    __syncthreads();

    const int rt0 = arow0 >> 5, kk0 = bcol0 >> 4;
    #pragma unroll
    for (int i = 0; i < 4; ++i) {
        const int tile = (i * 256 + t) >> 6;       // 0..15
        const int ln = t & 63;
        const int rt = tile >> 2, kk = tile & 3;
        const int row = rt * 32 + (ln & 31);
        const int kb = kk * 16 + (ln >> 5) * 8;
        const int src = row * 64 + (((kb >> 3) ^ (row & 7)) << 3);
        const size_t dst = ((size_t)(rt0 + rt) * 64 + (kk0 + kk)) * 512 + ln * 8;
        *(s8v*)&h1f[dst] = *(const s8v*)&hls[src];
        *(s8v*)&g1f[dst] = *(const s8v*)&gls[src];
    }
}

// ---------------------------------------------------------------------------
// mid (m97-faithful): fused dual GEMM + fused out K-split.
// 256 thr (4 waves), tile 128x64, grid (32,16) = 512 blocks (2-4 blocks/CU).
// Per kt (BK=32): each wave issues 6 global_load_lds w16 (A-h, A-g, B-W2,
// B-V frags, 24 frags total = 24 KB single buffer) -> barrier (vmcnt drain,
// hidden by co-resident blocks) -> 12 lane-linear ds_read_b128 + 8 MFMA ->
// barrier. Zero staging VALU, zero conflicts, B staged once (no reg dup).
// Frag slots: 0-7 A-h (rt*2+kk), 8-15 A-g, 16-19 B-W2 (nt*2+kk), 20-23 B-V.
// Wave-tile 64x32: wrt=wave&1 (rows), wn=wave>>1 (cols).
// Epilogue (R16 pattern, 64-col tile): h2 -> swizzled hls(16KB) + trace
// atomics; then per-wave 8-MFMA out-GEMM -> obuf atomics. by==0 adds b3.
// ---------------------------------------------------------------------------
__launch_bounds__(256)
__global__ void cnf_mid(const u16* __restrict__ h1f, const u16* __restrict__ g1f,
                        const u16* __restrict__ W2Tf, const u16* __restrict__ VTf,
                        const u16* __restrict__ W3Tf,
                        const float* __restrict__ b2, const float* __restrict__ b3,
                        float* __restrict__ obuf, float* __restrict__ trJ)
{
    __shared__ __align__(16) u16 lds[12288];   // 24 KB staging; epilogue hls 16 KB

    const int t = threadIdx.x;
    const int wave = t >> 6, lane = t & 63;
    const int wrt = wave & 1;          // row half (64 rows = 2 mtiles)
    const int wn  = wave >> 1;         // col half (32 cols = 1 ntile)
    const int bx = blockIdx.x;         // row tile 0..31
    const int by = blockIdx.y;         // col group 0..15 (64 cols)
    const int arow0 = bx * 128;

    // 6 staging sources for this wave (fid = wave*6 + i)
    const u16* src[6];
    #pragma unroll
    for (int i = 0; i < 6; ++i) {
        const int fid = wave * 6 + i;
        const u16* base; int rt;
        if (fid < 8)       { base = h1f;  rt = bx * 4 + (fid >> 1); }
        else if (fid < 16) { base = g1f;  rt = bx * 4 + ((fid - 8) >> 1); }
        else if (fid < 20) { base = W2Tf; rt = by * 2 + ((fid - 16) >> 1); }
        else               { base = VTf;  rt = by * 2 + ((fid - 20) >> 1); }
        src[i] = base + ((size_t)rt * 64 + (fid & 1)) * 512 + lane * 8;
    }
    u16* const dstw = &lds[wave * 6 * 512];

    f16v acc1[2], acc2[2];
    #pragma unroll
    for (int mt = 0; mt < 2; ++mt)
        #pragma unroll
        for (int r = 0; r < 16; ++r) { acc1[mt][r] = 0.f; acc2[mt][r] = 0.f; }

    const int lo = lane * 8;
    for (int kt = 0; kt < 32; ++kt) {
        #pragma unroll
        for (int i = 0; i < 6; ++i)
            gload_lds16(src[i] + (size_t)kt * 1024, dstw + i * 512);
        __syncthreads();   // vmcnt(0) drain -> LDS ready (hidden cross-block)

        #pragma unroll
        for (int ks = 0; ks < 2; ++ks) {
            s8v b1v = *(const s8v*)&lds[(16 + wn * 2 + ks) * 512 + lo];
            s8v b2v = *(const s8v*)&lds[(20 + wn * 2 + ks) * 512 + lo];
            #pragma unroll
            for (int mt = 0; mt < 2; ++mt) {
                const int fa = ((wrt * 2 + mt) * 2 + ks) * 512 + lo;
                s8v a1 = *(const s8v*)&lds[fa];
                s8v a2 = *(const s8v*)&lds[4096 + fa];
                acc1[mt] = __builtin_amdgcn_mfma_f32_32x32x16_bf16(a1, b1v, acc1[mt], 0, 0, 0);
                acc2[mt] = __builtin_amdgcn_mfma_f32_32x32x16_bf16(a2, b2v, acc2[mt], 0, 0, 0);
            }
        }
        __syncthreads();   // protect LDS overwrite
    }

    // ---- epilogue phase 1: h2 -> swizzled hls[128][64] + trace atomics ----
    u16* hls = &lds[0];
    const int l31 = lane & 31, lh = lane >> 5;
    #pragma unroll
    for (int mt = 0; mt < 2; ++mt) {
        const int coll = wn * 32 + l31;            // tile-local h2 col (0..63)
        const float bv = b2[by * 64 + coll];
        const int cc = coll >> 3, jj = coll & 7;
        float tr[16];
        #pragma unroll
        for (int r = 0; r < 16; ++r) {
            float hh = tanh_fast(acc1[mt][r] + bv);
            float gg = 1.f - hh * hh;
            const int row = wrt * 64 + mt * 32 + (r & 3) + ((r >> 2) << 3) + lh * 4;
            hls[row * 64 + ((cc ^ (row & 7)) << 3) + jj] = f2bf(hh);
            tr[r] = acc2[mt][r] * gg;
        }
        #pragma unroll
        for (int off = 1; off < 32; off <<= 1)
            #pragma unroll
            for (int r = 0; r < 16; ++r) tr[r] += __shfl_xor(tr[r], off);
        if (l31 == 0) {
            const int rowb = arow0 + (wrt * 2 + mt) * 32 + lh * 4;
            #pragma unroll
            for (int r = 0; r < 16; ++r)
                atomicAdd(&trJ[rowb + (r & 3) + ((r >> 2) << 3)], tr[r]);
        }
    }
    __syncthreads();

    // ---- epilogue phase 2: out partial = hls(128x64) @ W3[by-slice(64)] ----
    // wave-tile 32 rows x 64 cols: ort = wave; K = 64 -> kk in 0..3
    {
        const int ort = wave;
        f16v oacc[2];
        #pragma unroll
        for (int ni = 0; ni < 2; ++ni)
            #pragma unroll
            for (int r = 0; r < 16; ++r) oacc[ni][r] = 0.f;
        #pragma unroll
        for (int kk = 0; kk < 4; ++kk) {
            const int row = ort * 32 + l31;
            const int ch = (kk * 2 + lh) ^ (row & 7);
            s8v af = *(const s8v*)&hls[row * 64 + ch * 8];
            #pragma unroll
            for (int ni = 0; ni < 2; ++ni) {
                s8v bf = *(const s8v*)&W3Tf[((size_t)ni * 64 + by * 4 + kk) * 512 + lane * 8];
                oacc[ni] = __builtin_amdgcn_mfma_f32_32x32x16_bf16(af, bf, oacc[ni], 0, 0, 0);
            }
        }
        #pragma unroll
        for (int ni = 0; ni < 2; ++ni) {
            const int col = ni * 32 + l31;
            const float badd = (by == 0) ? b3[col] : 0.f;
            #pragma unroll
            for (int r = 0; r < 16; ++r) {
                const int row = arow0 + ort * 32 + (r & 3) + ((r >> 2) << 3) + lh * 4;
                atomicAdd(&obuf[(size_t)row * 64 + col], oacc[ni][r] + badd);
            }
        }
    }
}

// ---------------------------------------------------------------------------
// fin: out[:,1:65] = obuf; out[:,0] = -trJ.  (R16 verbatim)
// ---------------------------------------------------------------------------
__launch_bounds__(256)
__global__ void cnf_fin(const float* __restrict__ obuf, const float* __restrict__ trJ,
                        float* __restrict__ out)
{
    const int t = threadIdx.x;
    const int row0 = blockIdx.x * 16;
    const int c = t & 63, rr = t >> 6;
    #pragma unroll
    for (int i = 0; i < 4; ++i) {
        const int row = row0 + rr + i * 4;
        out[(size_t)row * 65 + 1 + c] = obuf[(size_t)row * 64 + c];
    }
    if (t < 16) out[(size_t)(row0 + t) * 65] = -trJ[row0 + t];
}

// ---------------------------------------------------------------------------
extern "C" void kernel_launch(void* const* d_in, const int* in_sizes, int n_in,
                              void* d_out, int out_size, void* d_ws, size_t ws_size,
                              hipStream_t stream) {
    const float* x  = (const float*)d_in[0];
    const float* W1 = (const float*)d_in[1];
    const float* b1 = (const float*)d_in[2];
    const float* W2 = (const float*)d_in[3];
    const float* b2 = (const float*)d_in[4];
    const float* W3 = (const float*)d_in[5];
    const float* b3 = (const float*)d_in[6];
    float* out = (float*)d_out;

    char* ws = (char*)d_ws;
    u16*   h1f = (u16*)(ws);                                  //  8 MB (frag layout)
    u16*   g1f = (u16*)(ws + (size_t)( 8u << 20));            //  8 MB (frag layout)
    float* obf = (float*)(ws + (size_t)(16u << 20));          //  1 MB (4096x64 f32)
    u16*   W2T = (u16*)(ws + (size_t)(24u << 20));            //  2 MB (frag layout)
    u16*   VTb = (u16*)(ws + (size_t)(26u << 20));            //  2 MB (frag layout)
    float* trJ = (float*)(ws + (size_t)(28u << 20));          // 16 KB
    u16*   xbb = (u16*)(ws + (size_t)(28u << 20) + 65536);    // 512 KB
    u16*   W1T = (u16*)(ws + (size_t)(28u << 20) + 65536 + 524288);             // 128 KB
    u16*   W3T = (u16*)(ws + (size_t)(28u << 20) + 65536 + 524288 + 131072);    // 128 KB (frag)

    cnf_prep <<<dim3(32, 32), 256, 0, stream>>>(x, W1, W2, W3, W2T, VTb, xbb, W1T, W3T, trJ, obf);
    cnf_gemm1<<<dim3(32, 16), 256, 0, stream>>>(xbb, W1T, b1, h1f, g1f);
    cnf_mid  <<<dim3(32, 16), 256, 0, stream>>>(h1f, g1f, W2T, VTb, W3T, b2, b3, obf, trJ);
    cnf_fin  <<<256,          256, 0, stream>>>(obf, trJ, out);
}